// Round 8
// baseline (663.666 us; speedup 1.0000x reference)
//
#include <hip/hip_runtime.h>
#include <hip/hip_bf16.h>

#define N_NODES 50000
#define N_EDGES 800000
#define NPATH 3
#define NBKT 196                    // ceil(50000/256) buckets per path
#define NBKT3 (NPATH * NBKT)        // 588
#define NCHUNKBLK 256               // blocks for count/scatter passes
#define CHUNK 9375                  // (3*800000)/256 exact

typedef __attribute__((ext_vector_type(8))) short short8;
typedef __attribute__((ext_vector_type(4))) float v4f;

// ---------------------------------------------------------------------------
// Pass A: per-block LDS histogram of bucket membership. NO global atomics.
// ---------------------------------------------------------------------------
__global__ __launch_bounds__(256) void blk_count_kernel(
    const int* __restrict__ ei, int* __restrict__ cntmat) {
  __shared__ int lcnt[NBKT3];
  const int t = threadIdx.x, blk = blockIdx.x;
  for (int j = t; j < NBKT3; j += 256) lcnt[j] = 0;
  __syncthreads();
  const int lo = blk * CHUNK, hi = lo + CHUNK;
  for (int idx = lo + t; idx < hi; idx += 256) {
    int p = idx / N_EDGES, e = idx - p * N_EDGES;
    int d = ei[p * 2 * N_EDGES + N_EDGES + e];
    atomicAdd(&lcnt[p * NBKT + (d >> 8)], 1);   // LDS atomic
  }
  __syncthreads();
  for (int j = t; j < NBKT3; j += 256) cntmat[blk * NBKT3 + j] = lcnt[j];
}

// ---------------------------------------------------------------------------
// Pass B: per-bucket scan across the 256 block-counts.
// ---------------------------------------------------------------------------
__global__ __launch_bounds__(256) void col_scan_kernel(
    const int* __restrict__ cntmat, int* __restrict__ pos, int* __restrict__ btot) {
  __shared__ int tmp[256];
  const int b = blockIdx.x, t = threadIdx.x;
  int v = cntmat[t * NBKT3 + b];
  tmp[t] = v;
  __syncthreads();
  for (int ofs = 1; ofs < 256; ofs <<= 1) {
    int x = (t >= ofs) ? tmp[t - ofs] : 0;
    __syncthreads();
    tmp[t] += x;
    __syncthreads();
  }
  pos[b * 256 + t] = tmp[t] - v;
  if (t == 255) btot[b] = tmp[255];
}

// ---------------------------------------------------------------------------
// Pass C: exclusive scan over the 588 bucket totals (single block).
// ---------------------------------------------------------------------------
__global__ __launch_bounds__(1024) void bucket_scan_kernel(
    const int* __restrict__ btot, int* __restrict__ boff) {
  __shared__ int tmp[1024];
  const int t = threadIdx.x;
  int v = (t < NBKT3) ? btot[t] : 0;
  tmp[t] = v;
  __syncthreads();
  for (int ofs = 1; ofs < 1024; ofs <<= 1) {
    int x = (t >= ofs) ? tmp[t - ofs] : 0;
    __syncthreads();
    tmp[t] += x;
    __syncthreads();
  }
  if (t < NBKT3) boff[t] = tmp[t] - v;
}

// ---------------------------------------------------------------------------
// Pass D: deterministic scatter. LDS cursors seeded with boff[b]+pos[b][blk].
// ---------------------------------------------------------------------------
__global__ __launch_bounds__(256) void scatter_det_kernel(
    const int* __restrict__ ei, const int* __restrict__ boff,
    const int* __restrict__ pos, int2* __restrict__ ebuf) {
  __shared__ int cursor[NBKT3];
  const int t = threadIdx.x, blk = blockIdx.x;
  for (int j = t; j < NBKT3; j += 256)
    cursor[j] = boff[j] + pos[j * 256 + blk];
  __syncthreads();
  const int lo = blk * CHUNK, hi = lo + CHUNK;
  for (int idx = lo + t; idx < hi; idx += 256) {
    int p = idx / N_EDGES, e = idx - p * N_EDGES;
    int s = ei[p * 2 * N_EDGES + e];
    int d = ei[p * 2 * N_EDGES + N_EDGES + e];
    int ps = atomicAdd(&cursor[p * NBKT + (d >> 8)], 1);   // LDS atomic
    ebuf[ps] = make_int2(s, d);
  }
}

// ---------------------------------------------------------------------------
// Pass E: per-bucket CSR finalize.
// ---------------------------------------------------------------------------
__global__ __launch_bounds__(256) void bucket_csr_kernel(
    const int2* __restrict__ ebuf, const int* __restrict__ boff,
    const int* __restrict__ btot,
    int* __restrict__ off3, int* __restrict__ deg3, int* __restrict__ csr_src) {
  __shared__ int cnt[256], excl[256], cur[256];
  const int b = blockIdx.x;
  const int t = threadIdx.x;
  const int p = b / NBKT;
  const int node_base = (b - p * NBKT) * 256;
  const int start = boff[b];
  const int ecount = btot[b];

  cnt[t] = 0;
  __syncthreads();
  for (int i = t; i < ecount; i += 256)
    atomicAdd(&cnt[ebuf[start + i].y & 255], 1);
  __syncthreads();

  int v = cnt[t];
  excl[t] = v;
  __syncthreads();
  for (int ofs = 1; ofs < 256; ofs <<= 1) {
    int x = (t >= ofs) ? excl[t - ofs] : 0;
    __syncthreads();
    excl[t] += x;
    __syncthreads();
  }
  int my_excl = excl[t] - v;
  cur[t] = my_excl;
  const int node = node_base + t;
  if (node < N_NODES) {
    off3[p * N_NODES + node] = start + my_excl;   // GLOBAL offset
    deg3[p * N_NODES + node] = v;
  }
  __syncthreads();

  for (int i = t; i < ecount; i += 256) {
    int2 e = ebuf[start + i];
    int pos2 = atomicAdd(&cur[e.y & 255], 1);
    csr_src[start + pos2] = e.x;
  }
}

// ---------------------------------------------------------------------------
// h split: h_hi = bf16(h), h_lo = bf16(h - h_hi). Once per launch.
// ---------------------------------------------------------------------------
__global__ __launch_bounds__(256) void hsplit_kernel(
    const float* __restrict__ h,
    __hip_bfloat16* __restrict__ h_hi, __hip_bfloat16* __restrict__ h_lo) {
  int i = blockIdx.x * 256 + threadIdx.x;
  if (i >= N_NODES * 128) return;
  float v = h[i];
  __hip_bfloat16 hb = __float2bfloat16(v);
  h_hi[i] = hb;
  h_lo[i] = __float2bfloat16(v - __bfloat162float(hb));
}

// ---------------------------------------------------------------------------
// Per-path prep 1: Walr[k][c] (128x16): c<8 -> W@al (head c), c>=8 -> W@ar.
// ---------------------------------------------------------------------------
__global__ __launch_bounds__(256) void walr_kernel(
    const float* __restrict__ W, const float* __restrict__ al,
    const float* __restrict__ ar, float* __restrict__ Walr) {
  int idx = blockIdx.x * 256 + threadIdx.x;
  if (idx >= 128 * 16) return;
  int k = idx >> 4, c = idx & 15;
  int h8 = c & 7;
  const float* av = (c < 8) ? al : ar;
  float s = 0.f;
  for (int d = 0; d < 32; d++)
    s = fmaf(W[k * 256 + h8 * 32 + d], av[h8 * 32 + d], s);
  Walr[k * 16 + c] = s;
}

// ---------------------------------------------------------------------------
// Per-path prep 2: W fragments (17 N-tiles; tile 16 = Walr), B-operand order.
// ---------------------------------------------------------------------------
__global__ __launch_bounds__(256) void wfrag_kernel(
    const float* __restrict__ W, const float* __restrict__ Walr,
    __hip_bfloat16* __restrict__ Wf_hi, __hip_bfloat16* __restrict__ Wf_lo) {
  int idx = blockIdx.x * 256 + threadIdx.x;
  if (idx >= 4 * 17 * 64) return;
  int lane = idx & 63;
  int tmp = idx >> 6;            // kc*17 + nt
  int nt = tmp % 17, kc = tmp / 17;
  int l15 = lane & 15, quad = lane >> 4;
  for (int j = 0; j < 8; j++) {
    int k = kc * 32 + quad * 8 + j;
    float v = (nt < 16) ? W[k * 256 + nt * 16 + l15] : Walr[k * 16 + l15];
    __hip_bfloat16 hb = __float2bfloat16(v);
    Wf_hi[(tmp * 64 + lane) * 8 + j] = hb;
    Wf_lo[(tmp * 64 + lane) * 8 + j] = __float2bfloat16(v - __bfloat162float(hb));
  }
}

// ---------------------------------------------------------------------------
// Per-path prep 3: sem_w fragments (8 kc x 8 nt), B-operand order.
// ---------------------------------------------------------------------------
__global__ __launch_bounds__(256) void bsem_kernel(
    const float* __restrict__ Ws,
    __hip_bfloat16* __restrict__ Bs_hi, __hip_bfloat16* __restrict__ Bs_lo) {
  int idx = blockIdx.x * 256 + threadIdx.x;
  if (idx >= 8 * 8 * 64) return;
  int lane = idx & 63;
  int tmp = idx >> 6;            // kc*8 + nt
  int nt = tmp & 7, kc = tmp >> 3;
  int l15 = lane & 15, quad = lane >> 4;
  for (int j = 0; j < 8; j++) {
    int k = kc * 32 + quad * 8 + j;
    float v = Ws[k * 128 + nt * 16 + l15];
    __hip_bfloat16 hb = __float2bfloat16(v);
    Bs_hi[(tmp * 64 + lane) * 8 + j] = hb;
    Bs_lo[(tmp * 64 + lane) * 8 + j] = __float2bfloat16(v - __bfloat162float(hb));
  }
}

// ---------------------------------------------------------------------------
// MFMA 1: feat = h @ W (bf16x3), 17th N-tile = [el|er]. 1 wave / 16 rows.
// ---------------------------------------------------------------------------
__global__ __launch_bounds__(64) void feat_mfma_kernel(
    const __hip_bfloat16* __restrict__ h_hi, const __hip_bfloat16* __restrict__ h_lo,
    const __hip_bfloat16* __restrict__ Wf_hi, const __hip_bfloat16* __restrict__ Wf_lo,
    __hip_bfloat16* __restrict__ feat, float* __restrict__ el, float* __restrict__ er) {
  const int lane = threadIdx.x;
  const int l15 = lane & 15, quad = lane >> 4;
  const int m0 = blockIdx.x * 16;
  const int mrow = m0 + l15;

  v4f acc[17];
#pragma unroll
  for (int nt = 0; nt < 17; nt++) acc[nt] = {0.f, 0.f, 0.f, 0.f};

#pragma unroll
  for (int kc = 0; kc < 4; kc++) {
    short8 ahi = *(const short8*)(h_hi + mrow * 128 + kc * 32 + quad * 8);
    short8 alo = *(const short8*)(h_lo + mrow * 128 + kc * 32 + quad * 8);
#pragma unroll
    for (int nt = 0; nt < 17; nt++) {
      const int o = ((kc * 17 + nt) * 64 + lane) * 8;
      short8 bhi = *(const short8*)(Wf_hi + o);
      short8 blo = *(const short8*)(Wf_lo + o);
      acc[nt] = __builtin_amdgcn_mfma_f32_16x16x32_bf16(ahi, bhi, acc[nt], 0, 0, 0);
      acc[nt] = __builtin_amdgcn_mfma_f32_16x16x32_bf16(ahi, blo, acc[nt], 0, 0, 0);
      acc[nt] = __builtin_amdgcn_mfma_f32_16x16x32_bf16(alo, bhi, acc[nt], 0, 0, 0);
    }
  }

#pragma unroll
  for (int nt = 0; nt < 16; nt++)
#pragma unroll
    for (int r = 0; r < 4; r++) {
      int m = m0 + quad * 4 + r;
      feat[(size_t)m * 256 + nt * 16 + l15] = __float2bfloat16(acc[nt][r]);
    }
#pragma unroll
  for (int r = 0; r < 4; r++) {
    int m = m0 + quad * 4 + r;
    float v = acc[16][r];
    if (l15 < 8) el[m * 8 + l15] = v;
    else         er[m * 8 + (l15 - 8)] = v;
  }
}

// ---------------------------------------------------------------------------
// Aggregate v2: per-dst gather with DEDUPLICATED attention.
// Chunk of 32 edges: phase 1 — 256 threads = (edge 0..31) x (head 0..7)
// compute ex once per (edge,head) into LDS; phase 2 — each thread (channel)
// does only fma(ex, feat_gather) + accD over the chunk.
// ---------------------------------------------------------------------------
__global__ __launch_bounds__(256) void aggregate_kernel(
    const int* __restrict__ csr_src, const int* __restrict__ off,
    const int* __restrict__ deg,
    const float* __restrict__ el, const float* __restrict__ er,
    const __hip_bfloat16* __restrict__ feat,
    __hip_bfloat16* __restrict__ eagg_hi, __hip_bfloat16* __restrict__ eagg_lo) {
  __shared__ float exw[32 * 8];   // exw[e*8 + h]
  __shared__ int sidx[32];
  const int d = blockIdx.x;
  const int t = threadIdx.x;      // channel 0..255 (phase 2)
  const int h = t >> 5;           // head (phase 2) == head (phase 1 mapping)
  const int e_local = t & 31;     // edge slot (phase 1)
  const float erh = er[d * 8 + h];
  const int start = off[d];
  const int n = deg[d];
  const int* lst = csr_src + start;

  float accN = 0.f, accD = 0.f;
  for (int base = 0; base < n; base += 32) {
    const int cnt = min(32, n - base);
    __syncthreads();                       // protect prior chunk's LDS reads
    if (e_local < cnt) {
      int s = lst[base + e_local];
      if (h == 0) sidx[e_local] = s;
      float x = el[s * 8 + h] + erh;
      x = x > 0.f ? x : 0.2f * x;
      exw[e_local * 8 + h] = __expf(x);
    }
    __syncthreads();

    int e = 0;
    for (; e + 4 <= cnt; e += 4) {
      int s0 = sidx[e + 0], s1 = sidx[e + 1], s2 = sidx[e + 2], s3 = sidx[e + 3];
      float x0 = exw[(e + 0) * 8 + h];
      float x1 = exw[(e + 1) * 8 + h];
      float x2 = exw[(e + 2) * 8 + h];
      float x3 = exw[(e + 3) * 8 + h];
      float v0 = __bfloat162float(feat[(size_t)s0 * 256 + t]);
      float v1 = __bfloat162float(feat[(size_t)s1 * 256 + t]);
      float v2 = __bfloat162float(feat[(size_t)s2 * 256 + t]);
      float v3 = __bfloat162float(feat[(size_t)s3 * 256 + t]);
      accN = fmaf(x0, v0, accN);  accD += x0;
      accN = fmaf(x1, v1, accN);  accD += x1;
      accN = fmaf(x2, v2, accN);  accD += x2;
      accN = fmaf(x3, v3, accN);  accD += x3;
    }
    for (; e < cnt; e++) {
      int s = sidx[e];
      float ex = exw[e * 8 + h];
      accN = fmaf(ex, __bfloat162float(feat[(size_t)s * 256 + t]), accN);
      accD += ex;
    }
  }

  float r = (n > 0) ? accN / accD : 0.f;
  r = r > 0.f ? r : (__expf(r) - 1.f);     // elu fused
  __hip_bfloat16 hb = __float2bfloat16(r);
  eagg_hi[(size_t)d * 256 + t] = hb;
  eagg_lo[(size_t)d * 256 + t] = __float2bfloat16(r - __bfloat162float(hb));
}

// ---------------------------------------------------------------------------
// MFMA 2: out (+)= eagg @ sem_w (bf16x3). mode 0: init with bias.
// ---------------------------------------------------------------------------
__global__ __launch_bounds__(64) void sem_mfma_kernel(
    const __hip_bfloat16* __restrict__ eagg_hi, const __hip_bfloat16* __restrict__ eagg_lo,
    const __hip_bfloat16* __restrict__ Bs_hi, const __hip_bfloat16* __restrict__ Bs_lo,
    const float* __restrict__ bias, float* __restrict__ out, int mode) {
  const int lane = threadIdx.x;
  const int l15 = lane & 15, quad = lane >> 4;
  const int m0 = blockIdx.x * 16;
  const int mrow = m0 + l15;

  v4f acc[8];
#pragma unroll
  for (int nt = 0; nt < 8; nt++) acc[nt] = {0.f, 0.f, 0.f, 0.f};

#pragma unroll
  for (int kc = 0; kc < 8; kc++) {
    short8 ahi = *(const short8*)(eagg_hi + (size_t)mrow * 256 + kc * 32 + quad * 8);
    short8 alo = *(const short8*)(eagg_lo + (size_t)mrow * 256 + kc * 32 + quad * 8);
#pragma unroll
    for (int nt = 0; nt < 8; nt++) {
      const int o = ((kc * 8 + nt) * 64 + lane) * 8;
      short8 bhi = *(const short8*)(Bs_hi + o);
      short8 blo = *(const short8*)(Bs_lo + o);
      acc[nt] = __builtin_amdgcn_mfma_f32_16x16x32_bf16(ahi, bhi, acc[nt], 0, 0, 0);
      acc[nt] = __builtin_amdgcn_mfma_f32_16x16x32_bf16(ahi, blo, acc[nt], 0, 0, 0);
      acc[nt] = __builtin_amdgcn_mfma_f32_16x16x32_bf16(alo, bhi, acc[nt], 0, 0, 0);
    }
  }

#pragma unroll
  for (int nt = 0; nt < 8; nt++)
#pragma unroll
    for (int r = 0; r < 4; r++) {
      int m = m0 + quad * 4 + r;
      size_t o = (size_t)m * 128 + nt * 16 + l15;
      float v = acc[nt][r];
      if (mode == 0) v += bias[nt * 16 + l15];
      else           v += out[o];
      out[o] = v;
    }
}

// ---------------------------------------------------------------------------
extern "C" void kernel_launch(void* const* d_in, const int* in_sizes, int n_in,
                              void* d_out, int out_size, void* d_ws, size_t ws_size,
                              hipStream_t stream) {
  const float* h      = (const float*)d_in[0];
  const int*   ei     = (const int*)d_in[1];
  const float* fc_w   = (const float*)d_in[2];
  const float* attn_l = (const float*)d_in[3];
  const float* attn_r = (const float*)d_in[4];
  const float* sem_w  = (const float*)d_in[5];
  const float* sem_b  = (const float*)d_in[6];
  float* out = (float*)d_out;

  // workspace layout (bytes) — total ~119.5 MB (<=132.8 MB proven safe)
  char* ws = (char*)d_ws;
  __hip_bfloat16* h_hi    = (__hip_bfloat16*)ws;                   // 12.8 MB
  __hip_bfloat16* h_lo    = (__hip_bfloat16*)(ws + 12800000);      // 12.8 MB
  __hip_bfloat16* feat    = (__hip_bfloat16*)(ws + 25600000);      // 25.6 MB
  int2*           ebuf    = (int2*)(ws + 51200000);                // 19.2 MB (union)
  __hip_bfloat16* eagg_hi = (__hip_bfloat16*)(ws + 51200000);      // 25.6 MB (union)
  __hip_bfloat16* eagg_lo = (__hip_bfloat16*)(ws + 76800000);      // 25.6 MB
  float* el      = (float*)(ws + 102400000);                       // 1.6 MB
  float* er      = (float*)(ws + 104000000);                       // 1.6 MB
  int*   deg3    = (int*)(ws + 105600000);                         // 0.6 MB
  int*   off3    = (int*)(ws + 106200000);                         // 0.6 MB
  int*   csr_src = (int*)(ws + 107400000);                         // 9.6 MB
  __hip_bfloat16* Wf_hi   = (__hip_bfloat16*)(ws + 117000000);     // 68 KB
  __hip_bfloat16* Wf_lo   = (__hip_bfloat16*)(ws + 117100000);     // 68 KB
  float*          Walr    = (float*)(ws + 117200000);              // 8 KB
  __hip_bfloat16* Bs_hi   = (__hip_bfloat16*)(ws + 117300000);     // 64 KB
  __hip_bfloat16* Bs_lo   = (__hip_bfloat16*)(ws + 117400000);     // 64 KB
  int*   cntmat  = (int*)(ws + 117500000);                         // 602 KB
  int*   posm    = (int*)(ws + 118150000);                         // 602 KB
  int*   btot    = (int*)(ws + 118800000);                         // 2.4 KB
  int*   boff    = (int*)(ws + 118810000);                         // 2.4 KB

  // --- CSR build: deterministic two-level counting sort (zero global atomics)
  blk_count_kernel<<<NCHUNKBLK, 256, 0, stream>>>(ei, cntmat);
  col_scan_kernel<<<NBKT3, 256, 0, stream>>>(cntmat, posm, btot);
  bucket_scan_kernel<<<1, 1024, 0, stream>>>(btot, boff);
  scatter_det_kernel<<<NCHUNKBLK, 256, 0, stream>>>(ei, boff, posm, ebuf);
  bucket_csr_kernel<<<NBKT3, 256, 0, stream>>>(ebuf, boff, btot, off3, deg3, csr_src);
  hsplit_kernel<<<(N_NODES * 128 + 255) / 256, 256, 0, stream>>>(h, h_hi, h_lo);

  for (int p = 0; p < NPATH; p++) {
    const float* W  = fc_w + (size_t)p * 128 * 256;
    const float* Ws = sem_w + (size_t)p * 256 * 128;

    walr_kernel<<<8, 256, 0, stream>>>(W, attn_l + p * 256, attn_r + p * 256, Walr);
    wfrag_kernel<<<17, 256, 0, stream>>>(W, Walr, Wf_hi, Wf_lo);
    bsem_kernel<<<16, 256, 0, stream>>>(Ws, Bs_hi, Bs_lo);

    feat_mfma_kernel<<<N_NODES / 16, 64, 0, stream>>>(
        h_hi, h_lo, Wf_hi, Wf_lo, feat, el, er);
    aggregate_kernel<<<N_NODES, 256, 0, stream>>>(
        csr_src, off3 + p * N_NODES, deg3 + p * N_NODES,
        el, er, feat, eagg_hi, eagg_lo);
    sem_mfma_kernel<<<N_NODES / 16, 64, 0, stream>>>(
        eagg_hi, eagg_lo, Bs_hi, Bs_lo, sem_b, out, p);
  }
}

// Round 9
// 620.751 us; speedup vs baseline: 1.0691x; 1.0691x over previous
//
#include <hip/hip_runtime.h>
#include <hip/hip_bf16.h>

#define N_NODES 50000
#define N_EDGES 800000
#define NPATH 3
#define NBKT 196                    // ceil(50000/256) buckets per path
#define NBKT3 (NPATH * NBKT)        // 588
#define NCHUNKBLK 256               // blocks for count/scatter passes
#define CHUNK 9375                  // (3*800000)/256 exact

typedef __attribute__((ext_vector_type(8))) short short8;
typedef __attribute__((ext_vector_type(4))) float v4f;

// RNE f32 -> bf16 bits, also returns the rounded-back float.
__device__ __forceinline__ short f2bf(float v, float* back) {
  unsigned u = __float_as_uint(v);
  unsigned r = (u + 0x7FFFu + ((u >> 16) & 1u)) >> 16;
  *back = __uint_as_float(r << 16);
  return (short)r;
}

// ---------------------------------------------------------------------------
// CSR build passes A-E (unchanged from R7; zero global atomics).
// ---------------------------------------------------------------------------
__global__ __launch_bounds__(256) void blk_count_kernel(
    const int* __restrict__ ei, int* __restrict__ cntmat) {
  __shared__ int lcnt[NBKT3];
  const int t = threadIdx.x, blk = blockIdx.x;
  for (int j = t; j < NBKT3; j += 256) lcnt[j] = 0;
  __syncthreads();
  const int lo = blk * CHUNK, hi = lo + CHUNK;
  for (int idx = lo + t; idx < hi; idx += 256) {
    int p = idx / N_EDGES, e = idx - p * N_EDGES;
    int d = ei[p * 2 * N_EDGES + N_EDGES + e];
    atomicAdd(&lcnt[p * NBKT + (d >> 8)], 1);   // LDS atomic
  }
  __syncthreads();
  for (int j = t; j < NBKT3; j += 256) cntmat[blk * NBKT3 + j] = lcnt[j];
}

__global__ __launch_bounds__(256) void col_scan_kernel(
    const int* __restrict__ cntmat, int* __restrict__ pos, int* __restrict__ btot) {
  __shared__ int tmp[256];
  const int b = blockIdx.x, t = threadIdx.x;
  int v = cntmat[t * NBKT3 + b];
  tmp[t] = v;
  __syncthreads();
  for (int ofs = 1; ofs < 256; ofs <<= 1) {
    int x = (t >= ofs) ? tmp[t - ofs] : 0;
    __syncthreads();
    tmp[t] += x;
    __syncthreads();
  }
  pos[b * 256 + t] = tmp[t] - v;
  if (t == 255) btot[b] = tmp[255];
}

__global__ __launch_bounds__(1024) void bucket_scan_kernel(
    const int* __restrict__ btot, int* __restrict__ boff) {
  __shared__ int tmp[1024];
  const int t = threadIdx.x;
  int v = (t < NBKT3) ? btot[t] : 0;
  tmp[t] = v;
  __syncthreads();
  for (int ofs = 1; ofs < 1024; ofs <<= 1) {
    int x = (t >= ofs) ? tmp[t - ofs] : 0;
    __syncthreads();
    tmp[t] += x;
    __syncthreads();
  }
  if (t < NBKT3) boff[t] = tmp[t] - v;
}

__global__ __launch_bounds__(256) void scatter_det_kernel(
    const int* __restrict__ ei, const int* __restrict__ boff,
    const int* __restrict__ pos, int2* __restrict__ ebuf) {
  __shared__ int cursor[NBKT3];
  const int t = threadIdx.x, blk = blockIdx.x;
  for (int j = t; j < NBKT3; j += 256)
    cursor[j] = boff[j] + pos[j * 256 + blk];
  __syncthreads();
  const int lo = blk * CHUNK, hi = lo + CHUNK;
  for (int idx = lo + t; idx < hi; idx += 256) {
    int p = idx / N_EDGES, e = idx - p * N_EDGES;
    int s = ei[p * 2 * N_EDGES + e];
    int d = ei[p * 2 * N_EDGES + N_EDGES + e];
    int ps = atomicAdd(&cursor[p * NBKT + (d >> 8)], 1);   // LDS atomic
    ebuf[ps] = make_int2(s, d);
  }
}

__global__ __launch_bounds__(256) void bucket_csr_kernel(
    const int2* __restrict__ ebuf, const int* __restrict__ boff,
    const int* __restrict__ btot,
    int* __restrict__ off3, int* __restrict__ deg3, int* __restrict__ csr_src) {
  __shared__ int cnt[256], excl[256], cur[256];
  const int b = blockIdx.x;
  const int t = threadIdx.x;
  const int p = b / NBKT;
  const int node_base = (b - p * NBKT) * 256;
  const int start = boff[b];
  const int ecount = btot[b];

  cnt[t] = 0;
  __syncthreads();
  for (int i = t; i < ecount; i += 256)
    atomicAdd(&cnt[ebuf[start + i].y & 255], 1);
  __syncthreads();

  int v = cnt[t];
  excl[t] = v;
  __syncthreads();
  for (int ofs = 1; ofs < 256; ofs <<= 1) {
    int x = (t >= ofs) ? excl[t - ofs] : 0;
    __syncthreads();
    excl[t] += x;
    __syncthreads();
  }
  int my_excl = excl[t] - v;
  cur[t] = my_excl;
  const int node = node_base + t;
  if (node < N_NODES) {
    off3[p * N_NODES + node] = start + my_excl;   // GLOBAL offset
    deg3[p * N_NODES + node] = v;
  }
  __syncthreads();

  for (int i = t; i < ecount; i += 256) {
    int2 e = ebuf[start + i];
    int pos2 = atomicAdd(&cur[e.y & 255], 1);
    csr_src[start + pos2] = e.x;
  }
}

// ---------------------------------------------------------------------------
// Fused prep (all paths, one dispatch): W fragments (17 N-tiles, tile 16 =
// W@[al|ar] computed inline) + sem_w fragments. B-operand order, hi/lo split.
// 33 blocks per path: unit 0..16 = wfrag, unit 17..32 = bsem.
// ---------------------------------------------------------------------------
__global__ __launch_bounds__(256) void prep_kernel(
    const float* __restrict__ fc_w, const float* __restrict__ attn_l,
    const float* __restrict__ attn_r, const float* __restrict__ sem_w,
    __hip_bfloat16* __restrict__ Wf_hi, __hip_bfloat16* __restrict__ Wf_lo,
    __hip_bfloat16* __restrict__ Bs_hi, __hip_bfloat16* __restrict__ Bs_lo) {
  const int p = blockIdx.x / 33;
  const int unit = blockIdx.x % 33;
  const int t = threadIdx.x;
  if (unit < 17) {
    const float* W = fc_w + (size_t)p * 128 * 256;
    int idx = unit * 256 + t;        // < 4352 = 4*17*64
    int lane = idx & 63;
    int tmp = idx >> 6;              // kc*17 + nt
    int nt = tmp % 17, kc = tmp / 17;
    int l15 = lane & 15, quad = lane >> 4;
    __hip_bfloat16* oh = Wf_hi + (size_t)p * 34816;
    __hip_bfloat16* ol = Wf_lo + (size_t)p * 34816;
    for (int j = 0; j < 8; j++) {
      int k = kc * 32 + quad * 8 + j;
      float v;
      if (nt < 16) {
        v = W[k * 256 + nt * 16 + l15];
      } else {
        int h8 = l15 & 7;
        const float* av = ((l15 < 8) ? attn_l : attn_r) + (size_t)p * 256 + h8 * 32;
        v = 0.f;
        for (int dd = 0; dd < 32; dd++)
          v = fmaf(W[k * 256 + h8 * 32 + dd], av[dd], v);
      }
      float back;
      short hb = f2bf(v, &back);
      float back2;
      short lb = f2bf(v - back, &back2);
      ((short*)oh)[(tmp * 64 + lane) * 8 + j] = hb;
      ((short*)ol)[(tmp * 64 + lane) * 8 + j] = lb;
    }
  } else {
    const float* Ws = sem_w + (size_t)p * 256 * 128;
    int idx = (unit - 17) * 256 + t; // < 4096 = 8*8*64
    int lane = idx & 63;
    int tmp = idx >> 6;              // kc*8 + nt
    int nt = tmp & 7, kc = tmp >> 3;
    int l15 = lane & 15, quad = lane >> 4;
    __hip_bfloat16* oh = Bs_hi + (size_t)p * 32768;
    __hip_bfloat16* ol = Bs_lo + (size_t)p * 32768;
    for (int j = 0; j < 8; j++) {
      int k = kc * 32 + quad * 8 + j;
      float v = Ws[k * 128 + nt * 16 + l15];
      float back;
      short hb = f2bf(v, &back);
      float back2;
      short lb = f2bf(v - back, &back2);
      ((short*)oh)[(tmp * 64 + lane) * 8 + j] = hb;
      ((short*)ol)[(tmp * 64 + lane) * 8 + j] = lb;
    }
  }
}

// ---------------------------------------------------------------------------
// MFMA 1: feat = h @ W (bf16x3), in-register f32->hi/lo split of h,
// 17th N-tile = [el|er]. 1 wave / 16 rows.
// ---------------------------------------------------------------------------
__global__ __launch_bounds__(64) void feat_mfma_kernel(
    const float* __restrict__ h,
    const __hip_bfloat16* __restrict__ Wf_hi, const __hip_bfloat16* __restrict__ Wf_lo,
    __hip_bfloat16* __restrict__ feat, float* __restrict__ el, float* __restrict__ er) {
  const int lane = threadIdx.x;
  const int l15 = lane & 15, quad = lane >> 4;
  const int m0 = blockIdx.x * 16;
  const int mrow = m0 + l15;

  v4f acc[17];
#pragma unroll
  for (int nt = 0; nt < 17; nt++) acc[nt] = {0.f, 0.f, 0.f, 0.f};

#pragma unroll
  for (int kc = 0; kc < 4; kc++) {
    const float* hrow = h + (size_t)mrow * 128 + kc * 32 + quad * 8;
    float4 fa = *(const float4*)hrow;
    float4 fb = *(const float4*)(hrow + 4);
    float fv[8] = {fa.x, fa.y, fa.z, fa.w, fb.x, fb.y, fb.z, fb.w};
    short8 ahi, alo;
#pragma unroll
    for (int q = 0; q < 8; q++) {
      float back;
      ahi[q] = f2bf(fv[q], &back);
      float back2;
      alo[q] = f2bf(fv[q] - back, &back2);
    }
#pragma unroll
    for (int nt = 0; nt < 17; nt++) {
      const int o = ((kc * 17 + nt) * 64 + lane) * 8;
      short8 bhi = *(const short8*)(Wf_hi + o);
      short8 blo = *(const short8*)(Wf_lo + o);
      acc[nt] = __builtin_amdgcn_mfma_f32_16x16x32_bf16(ahi, bhi, acc[nt], 0, 0, 0);
      acc[nt] = __builtin_amdgcn_mfma_f32_16x16x32_bf16(ahi, blo, acc[nt], 0, 0, 0);
      acc[nt] = __builtin_amdgcn_mfma_f32_16x16x32_bf16(alo, bhi, acc[nt], 0, 0, 0);
    }
  }

#pragma unroll
  for (int nt = 0; nt < 16; nt++)
#pragma unroll
    for (int r = 0; r < 4; r++) {
      int m = m0 + quad * 4 + r;
      feat[(size_t)m * 256 + nt * 16 + l15] = __float2bfloat16(acc[nt][r]);
    }
#pragma unroll
  for (int r = 0; r < 4; r++) {
    int m = m0 + quad * 4 + r;
    float v = acc[16][r];
    if (l15 < 8) el[m * 8 + l15] = v;
    else         er[m * 8 + (l15 - 8)] = v;
  }
}

// ---------------------------------------------------------------------------
// Aggregate v3: wave-per-edge. Lane l handles channels 4l..4l+3 (ushort4 =
// one 512B row read per wave per edge). ex computed in-registers (8-way
// redundant per head, barrier-free). Wave w takes edges j = w, w+4, ...
// Cross-wave reduce via 4KB LDS at the end. Fused softmax + elu.
// ---------------------------------------------------------------------------
__global__ __launch_bounds__(256) void aggregate_kernel(
    const int* __restrict__ csr_src, const int* __restrict__ off,
    const int* __restrict__ deg,
    const float* __restrict__ el, const float* __restrict__ er,
    const __hip_bfloat16* __restrict__ feat,
    __hip_bfloat16* __restrict__ eagg_hi, __hip_bfloat16* __restrict__ eagg_lo) {
  __shared__ float redN[4][256];
  __shared__ float redD[4][8];
  const int d = blockIdx.x;
  const int t = threadIdx.x;
  const int w = t >> 6, lane = t & 63;
  const int hh = lane >> 3;            // head of this lane's 4 channels
  const float erh = er[d * 8 + hh];
  const int n = deg[d];
  const int* lst = csr_src + off[d];
  const ushort* fp = (const ushort*)feat;

  float aN0 = 0.f, aN1 = 0.f, aN2 = 0.f, aN3 = 0.f, aD = 0.f;

  int j = w;
  for (; j + 12 < n; j += 16) {
    int s0 = lst[j], s1 = lst[j + 4], s2 = lst[j + 8], s3 = lst[j + 12];
    float x0 = el[s0 * 8 + hh] + erh;
    float x1 = el[s1 * 8 + hh] + erh;
    float x2 = el[s2 * 8 + hh] + erh;
    float x3 = el[s3 * 8 + hh] + erh;
    ushort4 f0 = *(const ushort4*)(fp + (size_t)s0 * 256 + lane * 4);
    ushort4 f1 = *(const ushort4*)(fp + (size_t)s1 * 256 + lane * 4);
    ushort4 f2 = *(const ushort4*)(fp + (size_t)s2 * 256 + lane * 4);
    ushort4 f3 = *(const ushort4*)(fp + (size_t)s3 * 256 + lane * 4);
    x0 = x0 > 0.f ? x0 : 0.2f * x0;  float e0 = __expf(x0);
    x1 = x1 > 0.f ? x1 : 0.2f * x1;  float e1 = __expf(x1);
    x2 = x2 > 0.f ? x2 : 0.2f * x2;  float e2 = __expf(x2);
    x3 = x3 > 0.f ? x3 : 0.2f * x3;  float e3 = __expf(x3);
    aD += e0 + e1 + e2 + e3;
    aN0 = fmaf(e0, __uint_as_float((unsigned)f0.x << 16), aN0);
    aN1 = fmaf(e0, __uint_as_float((unsigned)f0.y << 16), aN1);
    aN2 = fmaf(e0, __uint_as_float((unsigned)f0.z << 16), aN2);
    aN3 = fmaf(e0, __uint_as_float((unsigned)f0.w << 16), aN3);
    aN0 = fmaf(e1, __uint_as_float((unsigned)f1.x << 16), aN0);
    aN1 = fmaf(e1, __uint_as_float((unsigned)f1.y << 16), aN1);
    aN2 = fmaf(e1, __uint_as_float((unsigned)f1.z << 16), aN2);
    aN3 = fmaf(e1, __uint_as_float((unsigned)f1.w << 16), aN3);
    aN0 = fmaf(e2, __uint_as_float((unsigned)f2.x << 16), aN0);
    aN1 = fmaf(e2, __uint_as_float((unsigned)f2.y << 16), aN1);
    aN2 = fmaf(e2, __uint_as_float((unsigned)f2.z << 16), aN2);
    aN3 = fmaf(e2, __uint_as_float((unsigned)f2.w << 16), aN3);
    aN0 = fmaf(e3, __uint_as_float((unsigned)f3.x << 16), aN0);
    aN1 = fmaf(e3, __uint_as_float((unsigned)f3.y << 16), aN1);
    aN2 = fmaf(e3, __uint_as_float((unsigned)f3.z << 16), aN2);
    aN3 = fmaf(e3, __uint_as_float((unsigned)f3.w << 16), aN3);
  }
  for (; j < n; j += 4) {
    int s = lst[j];
    float x = el[s * 8 + hh] + erh;
    ushort4 f0 = *(const ushort4*)(fp + (size_t)s * 256 + lane * 4);
    x = x > 0.f ? x : 0.2f * x;
    float e0 = __expf(x);
    aD += e0;
    aN0 = fmaf(e0, __uint_as_float((unsigned)f0.x << 16), aN0);
    aN1 = fmaf(e0, __uint_as_float((unsigned)f0.y << 16), aN1);
    aN2 = fmaf(e0, __uint_as_float((unsigned)f0.z << 16), aN2);
    aN3 = fmaf(e0, __uint_as_float((unsigned)f0.w << 16), aN3);
  }

  *(float4*)&redN[w][lane * 4] = make_float4(aN0, aN1, aN2, aN3);
  if ((lane & 7) == 0) redD[w][hh] = aD;
  __syncthreads();

  // t = channel
  float accN = redN[0][t] + redN[1][t] + redN[2][t] + redN[3][t];
  int h2 = t >> 5;
  float accD = redD[0][h2] + redD[1][h2] + redD[2][h2] + redD[3][h2];
  float r = (n > 0) ? accN / accD : 0.f;
  r = r > 0.f ? r : (__expf(r) - 1.f);   // elu fused
  float back;
  short hb = f2bf(r, &back);
  float back2;
  short lb = f2bf(r - back, &back2);
  ((short*)eagg_hi)[(size_t)d * 256 + t] = hb;
  ((short*)eagg_lo)[(size_t)d * 256 + t] = lb;
}

// ---------------------------------------------------------------------------
// MFMA 2: out (+)= eagg @ sem_w (bf16x3). mode 0: init with bias.
// ---------------------------------------------------------------------------
__global__ __launch_bounds__(64) void sem_mfma_kernel(
    const __hip_bfloat16* __restrict__ eagg_hi, const __hip_bfloat16* __restrict__ eagg_lo,
    const __hip_bfloat16* __restrict__ Bs_hi, const __hip_bfloat16* __restrict__ Bs_lo,
    const float* __restrict__ bias, float* __restrict__ out, int mode) {
  const int lane = threadIdx.x;
  const int l15 = lane & 15, quad = lane >> 4;
  const int m0 = blockIdx.x * 16;
  const int mrow = m0 + l15;

  v4f acc[8];
#pragma unroll
  for (int nt = 0; nt < 8; nt++) acc[nt] = {0.f, 0.f, 0.f, 0.f};

#pragma unroll
  for (int kc = 0; kc < 8; kc++) {
    short8 ahi = *(const short8*)(eagg_hi + (size_t)mrow * 256 + kc * 32 + quad * 8);
    short8 alo = *(const short8*)(eagg_lo + (size_t)mrow * 256 + kc * 32 + quad * 8);
#pragma unroll
    for (int nt = 0; nt < 8; nt++) {
      const int o = ((kc * 8 + nt) * 64 + lane) * 8;
      short8 bhi = *(const short8*)(Bs_hi + o);
      short8 blo = *(const short8*)(Bs_lo + o);
      acc[nt] = __builtin_amdgcn_mfma_f32_16x16x32_bf16(ahi, bhi, acc[nt], 0, 0, 0);
      acc[nt] = __builtin_amdgcn_mfma_f32_16x16x32_bf16(ahi, blo, acc[nt], 0, 0, 0);
      acc[nt] = __builtin_amdgcn_mfma_f32_16x16x32_bf16(alo, bhi, acc[nt], 0, 0, 0);
    }
  }

#pragma unroll
  for (int nt = 0; nt < 8; nt++)
#pragma unroll
    for (int r = 0; r < 4; r++) {
      int m = m0 + quad * 4 + r;
      size_t o = (size_t)m * 128 + nt * 16 + l15;
      float v = acc[nt][r];
      if (mode == 0) v += bias[nt * 16 + l15];
      else           v += out[o];
      out[o] = v;
    }
}

// ---------------------------------------------------------------------------
extern "C" void kernel_launch(void* const* d_in, const int* in_sizes, int n_in,
                              void* d_out, int out_size, void* d_ws, size_t ws_size,
                              hipStream_t stream) {
  const float* h      = (const float*)d_in[0];
  const int*   ei     = (const int*)d_in[1];
  const float* fc_w   = (const float*)d_in[2];
  const float* attn_l = (const float*)d_in[3];
  const float* attn_r = (const float*)d_in[4];
  const float* sem_w  = (const float*)d_in[5];
  const float* sem_b  = (const float*)d_in[6];
  float* out = (float*)d_out;

  // workspace layout (bytes) — total ~94.3 MB (<=132.8 MB proven safe)
  // ebuf (19.2 MB) time-shares the eagg region (used only before aggregate).
  char* ws = (char*)d_ws;
  __hip_bfloat16* feat    = (__hip_bfloat16*)ws;                   // 25.6 MB
  int2*           ebuf    = (int2*)(ws + 25600000);                // 19.2 MB (union)
  __hip_bfloat16* eagg_hi = (__hip_bfloat16*)(ws + 25600000);      // 25.6 MB (union)
  __hip_bfloat16* eagg_lo = (__hip_bfloat16*)(ws + 51200000);      // 25.6 MB
  float* el      = (float*)(ws + 76800000);                        // 1.6 MB
  float* er      = (float*)(ws + 78400000);                        // 1.6 MB
  int*   deg3    = (int*)(ws + 80000000);                          // 0.6 MB
  int*   off3    = (int*)(ws + 80600000);                          // 0.6 MB
  int*   csr_src = (int*)(ws + 81200000);                          // 9.6 MB
  int*   cntmat  = (int*)(ws + 90800000);                          // 602 KB
  int*   posm    = (int*)(ws + 91500000);                          // 602 KB
  int*   btot    = (int*)(ws + 92200000);                          // 2.4 KB
  int*   boff    = (int*)(ws + 92210000);                          // 2.4 KB
  __hip_bfloat16* Wf_hi = (__hip_bfloat16*)(ws + 92300000);        // 3x69632 B
  __hip_bfloat16* Wf_lo = (__hip_bfloat16*)(ws + 92600000);        // 3x69632 B
  __hip_bfloat16* Bs_hi = (__hip_bfloat16*)(ws + 92900000);        // 3x65536 B
  __hip_bfloat16* Bs_lo = (__hip_bfloat16*)(ws + 93200000);        // 3x65536 B

  // --- CSR build (deterministic counting sort) + fused weight prep ---
  blk_count_kernel<<<NCHUNKBLK, 256, 0, stream>>>(ei, cntmat);
  col_scan_kernel<<<NBKT3, 256, 0, stream>>>(cntmat, posm, btot);
  bucket_scan_kernel<<<1, 1024, 0, stream>>>(btot, boff);
  scatter_det_kernel<<<NCHUNKBLK, 256, 0, stream>>>(ei, boff, posm, ebuf);
  bucket_csr_kernel<<<NBKT3, 256, 0, stream>>>(ebuf, boff, btot, off3, deg3, csr_src);
  prep_kernel<<<NPATH * 33, 256, 0, stream>>>(fc_w, attn_l, attn_r, sem_w,
                                              Wf_hi, Wf_lo, Bs_hi, Bs_lo);

  for (int p = 0; p < NPATH; p++) {
    feat_mfma_kernel<<<N_NODES / 16, 64, 0, stream>>>(
        h, Wf_hi + (size_t)p * 34816, Wf_lo + (size_t)p * 34816, feat, el, er);
    aggregate_kernel<<<N_NODES, 256, 0, stream>>>(
        csr_src, off3 + p * N_NODES, deg3 + p * N_NODES,
        el, er, feat, eagg_hi, eagg_lo);
    sem_mfma_kernel<<<N_NODES / 16, 64, 0, stream>>>(
        eagg_hi, eagg_lo, Bs_hi + (size_t)p * 32768, Bs_lo + (size_t)p * 32768,
        sem_b, out, p);
  }
}

// Round 10
// 492.105 us; speedup vs baseline: 1.3486x; 1.2614x over previous
//
#include <hip/hip_runtime.h>
#include <hip/hip_bf16.h>

#define N_NODES 50000
#define N_EDGES 800000
#define NPATH 3
#define NBKT 196                    // ceil(50000/256) buckets per path
#define NBKT3 (NPATH * NBKT)        // 588
#define NCHUNKBLK 256               // blocks for count/scatter passes
#define CHUNK 9375                  // (3*800000)/256 exact
#define LDS_STRIDE 260              // 256 + 4 pad -> 2-way banks on MFMA reads

typedef __attribute__((ext_vector_type(8))) short short8;
typedef __attribute__((ext_vector_type(4))) float v4f;

// RNE f32 -> bf16 bits, also returns the rounded-back float.
__device__ __forceinline__ short f2bf(float v, float* back) {
  unsigned u = __float_as_uint(v);
  unsigned r = (u + 0x7FFFu + ((u >> 16) & 1u)) >> 16;
  *back = __uint_as_float(r << 16);
  return (short)r;
}

// ---------------------------------------------------------------------------
// CSR build passes A-E (unchanged from R7; zero global atomics).
// ---------------------------------------------------------------------------
__global__ __launch_bounds__(256) void blk_count_kernel(
    const int* __restrict__ ei, int* __restrict__ cntmat) {
  __shared__ int lcnt[NBKT3];
  const int t = threadIdx.x, blk = blockIdx.x;
  for (int j = t; j < NBKT3; j += 256) lcnt[j] = 0;
  __syncthreads();
  const int lo = blk * CHUNK, hi = lo + CHUNK;
  for (int idx = lo + t; idx < hi; idx += 256) {
    int p = idx / N_EDGES, e = idx - p * N_EDGES;
    int d = ei[p * 2 * N_EDGES + N_EDGES + e];
    atomicAdd(&lcnt[p * NBKT + (d >> 8)], 1);   // LDS atomic
  }
  __syncthreads();
  for (int j = t; j < NBKT3; j += 256) cntmat[blk * NBKT3 + j] = lcnt[j];
}

__global__ __launch_bounds__(256) void col_scan_kernel(
    const int* __restrict__ cntmat, int* __restrict__ pos, int* __restrict__ btot) {
  __shared__ int tmp[256];
  const int b = blockIdx.x, t = threadIdx.x;
  int v = cntmat[t * NBKT3 + b];
  tmp[t] = v;
  __syncthreads();
  for (int ofs = 1; ofs < 256; ofs <<= 1) {
    int x = (t >= ofs) ? tmp[t - ofs] : 0;
    __syncthreads();
    tmp[t] += x;
    __syncthreads();
  }
  pos[b * 256 + t] = tmp[t] - v;
  if (t == 255) btot[b] = tmp[255];
}

__global__ __launch_bounds__(1024) void bucket_scan_kernel(
    const int* __restrict__ btot, int* __restrict__ boff) {
  __shared__ int tmp[1024];
  const int t = threadIdx.x;
  int v = (t < NBKT3) ? btot[t] : 0;
  tmp[t] = v;
  __syncthreads();
  for (int ofs = 1; ofs < 1024; ofs <<= 1) {
    int x = (t >= ofs) ? tmp[t - ofs] : 0;
    __syncthreads();
    tmp[t] += x;
    __syncthreads();
  }
  if (t < NBKT3) boff[t] = tmp[t] - v;
}

__global__ __launch_bounds__(256) void scatter_det_kernel(
    const int* __restrict__ ei, const int* __restrict__ boff,
    const int* __restrict__ pos, int2* __restrict__ ebuf) {
  __shared__ int cursor[NBKT3];
  const int t = threadIdx.x, blk = blockIdx.x;
  for (int j = t; j < NBKT3; j += 256)
    cursor[j] = boff[j] + pos[j * 256 + blk];
  __syncthreads();
  const int lo = blk * CHUNK, hi = lo + CHUNK;
  for (int idx = lo + t; idx < hi; idx += 256) {
    int p = idx / N_EDGES, e = idx - p * N_EDGES;
    int s = ei[p * 2 * N_EDGES + e];
    int d = ei[p * 2 * N_EDGES + N_EDGES + e];
    int ps = atomicAdd(&cursor[p * NBKT + (d >> 8)], 1);   // LDS atomic
    ebuf[ps] = make_int2(s, d);
  }
}

__global__ __launch_bounds__(256) void bucket_csr_kernel(
    const int2* __restrict__ ebuf, const int* __restrict__ boff,
    const int* __restrict__ btot,
    int* __restrict__ off3, int* __restrict__ deg3, int* __restrict__ csr_src) {
  __shared__ int cnt[256], excl[256], cur[256];
  const int b = blockIdx.x;
  const int t = threadIdx.x;
  const int p = b / NBKT;
  const int node_base = (b - p * NBKT) * 256;
  const int start = boff[b];
  const int ecount = btot[b];

  cnt[t] = 0;
  __syncthreads();
  for (int i = t; i < ecount; i += 256)
    atomicAdd(&cnt[ebuf[start + i].y & 255], 1);
  __syncthreads();

  int v = cnt[t];
  excl[t] = v;
  __syncthreads();
  for (int ofs = 1; ofs < 256; ofs <<= 1) {
    int x = (t >= ofs) ? excl[t - ofs] : 0;
    __syncthreads();
    excl[t] += x;
    __syncthreads();
  }
  int my_excl = excl[t] - v;
  cur[t] = my_excl;
  const int node = node_base + t;
  if (node < N_NODES) {
    off3[p * N_NODES + node] = start + my_excl;   // GLOBAL offset
    deg3[p * N_NODES + node] = v;
  }
  __syncthreads();

  for (int i = t; i < ecount; i += 256) {
    int2 e = ebuf[start + i];
    int pos2 = atomicAdd(&cur[e.y & 255], 1);
    csr_src[start + pos2] = e.x;
  }
}

// ---------------------------------------------------------------------------
// Fused prep (all paths, one dispatch): W fragments (17 N-tiles, tile 16 =
// W@[al|ar] computed inline) + sem_w fragments. B-operand order, hi/lo split.
// ---------------------------------------------------------------------------
__global__ __launch_bounds__(256) void prep_kernel(
    const float* __restrict__ fc_w, const float* __restrict__ attn_l,
    const float* __restrict__ attn_r, const float* __restrict__ sem_w,
    __hip_bfloat16* __restrict__ Wf_hi, __hip_bfloat16* __restrict__ Wf_lo,
    __hip_bfloat16* __restrict__ Bs_hi, __hip_bfloat16* __restrict__ Bs_lo) {
  const int p = blockIdx.x / 33;
  const int unit = blockIdx.x % 33;
  const int t = threadIdx.x;
  if (unit < 17) {
    const float* W = fc_w + (size_t)p * 128 * 256;
    int idx = unit * 256 + t;        // < 4352 = 4*17*64
    int lane = idx & 63;
    int tmp = idx >> 6;              // kc*17 + nt
    int nt = tmp % 17, kc = tmp / 17;
    int l15 = lane & 15, quad = lane >> 4;
    __hip_bfloat16* oh = Wf_hi + (size_t)p * 34816;
    __hip_bfloat16* ol = Wf_lo + (size_t)p * 34816;
    for (int j = 0; j < 8; j++) {
      int k = kc * 32 + quad * 8 + j;
      float v;
      if (nt < 16) {
        v = W[k * 256 + nt * 16 + l15];
      } else {
        int h8 = l15 & 7;
        const float* av = ((l15 < 8) ? attn_l : attn_r) + (size_t)p * 256 + h8 * 32;
        v = 0.f;
        for (int dd = 0; dd < 32; dd++)
          v = fmaf(W[k * 256 + h8 * 32 + dd], av[dd], v);
      }
      float back, back2;
      short hb = f2bf(v, &back);
      short lb = f2bf(v - back, &back2);
      ((short*)oh)[(tmp * 64 + lane) * 8 + j] = hb;
      ((short*)ol)[(tmp * 64 + lane) * 8 + j] = lb;
    }
  } else {
    const float* Ws = sem_w + (size_t)p * 256 * 128;
    int idx = (unit - 17) * 256 + t; // < 4096 = 8*8*64
    int lane = idx & 63;
    int tmp = idx >> 6;              // kc*8 + nt
    int nt = tmp & 7, kc = tmp >> 3;
    int l15 = lane & 15, quad = lane >> 4;
    __hip_bfloat16* oh = Bs_hi + (size_t)p * 32768;
    __hip_bfloat16* ol = Bs_lo + (size_t)p * 32768;
    for (int j = 0; j < 8; j++) {
      int k = kc * 32 + quad * 8 + j;
      float v = Ws[k * 128 + nt * 16 + l15];
      float back, back2;
      short hb = f2bf(v, &back);
      short lb = f2bf(v - back, &back2);
      ((short*)oh)[(tmp * 64 + lane) * 8 + j] = hb;
      ((short*)ol)[(tmp * 64 + lane) * 8 + j] = lb;
    }
  }
}

// ---------------------------------------------------------------------------
// MFMA 1 (all 3 paths in one dispatch, grid.y = p): feat = h @ W (bf16x3),
// in-register f32->hi/lo split of h, 17th N-tile = [el|er]. 1 wave / 16 rows.
// ---------------------------------------------------------------------------
__global__ __launch_bounds__(64) void feat_mfma_kernel(
    const float* __restrict__ h,
    const __hip_bfloat16* __restrict__ Wf_hi_all,
    const __hip_bfloat16* __restrict__ Wf_lo_all,
    __hip_bfloat16* __restrict__ feat3, float* __restrict__ el3,
    float* __restrict__ er3) {
  const int p = blockIdx.y;
  const __hip_bfloat16* Wf_hi = Wf_hi_all + (size_t)p * 34816;
  const __hip_bfloat16* Wf_lo = Wf_lo_all + (size_t)p * 34816;
  __hip_bfloat16* feat = feat3 + (size_t)p * N_NODES * 256;
  float* el = el3 + (size_t)p * N_NODES * 8;
  float* er = er3 + (size_t)p * N_NODES * 8;

  const int lane = threadIdx.x;
  const int l15 = lane & 15, quad = lane >> 4;
  const int m0 = blockIdx.x * 16;
  const int mrow = m0 + l15;

  v4f acc[17];
#pragma unroll
  for (int nt = 0; nt < 17; nt++) acc[nt] = {0.f, 0.f, 0.f, 0.f};

#pragma unroll
  for (int kc = 0; kc < 4; kc++) {
    const float* hrow = h + (size_t)mrow * 128 + kc * 32 + quad * 8;
    float4 fa = *(const float4*)hrow;
    float4 fb = *(const float4*)(hrow + 4);
    float fv[8] = {fa.x, fa.y, fa.z, fa.w, fb.x, fb.y, fb.z, fb.w};
    short8 ahi, alo;
#pragma unroll
    for (int q = 0; q < 8; q++) {
      float back, back2;
      ahi[q] = f2bf(fv[q], &back);
      alo[q] = f2bf(fv[q] - back, &back2);
    }
#pragma unroll
    for (int nt = 0; nt < 17; nt++) {
      const int o = ((kc * 17 + nt) * 64 + lane) * 8;
      short8 bhi = *(const short8*)(Wf_hi + o);
      short8 blo = *(const short8*)(Wf_lo + o);
      acc[nt] = __builtin_amdgcn_mfma_f32_16x16x32_bf16(ahi, bhi, acc[nt], 0, 0, 0);
      acc[nt] = __builtin_amdgcn_mfma_f32_16x16x32_bf16(ahi, blo, acc[nt], 0, 0, 0);
      acc[nt] = __builtin_amdgcn_mfma_f32_16x16x32_bf16(alo, bhi, acc[nt], 0, 0, 0);
    }
  }

#pragma unroll
  for (int nt = 0; nt < 16; nt++)
#pragma unroll
    for (int r = 0; r < 4; r++) {
      int m = m0 + quad * 4 + r;
      feat[(size_t)m * 256 + nt * 16 + l15] = __float2bfloat16(acc[nt][r]);
    }
#pragma unroll
  for (int r = 0; r < 4; r++) {
    int m = m0 + quad * 4 + r;
    float v = acc[16][r];
    if (l15 < 8) el[m * 8 + l15] = v;
    else         er[m * 8 + (l15 - 8)] = v;
  }
}

// ---------------------------------------------------------------------------
// Fused aggregate + semantic GEMM. 512 threads (8 waves) per block; block
// handles 16 dst nodes. Edge phase: wave w solo-aggregates nodes 2w, 2w+1
// (lane l = channels 4l..4l+3, ushort4 row loads, in-register ex) and stores
// elu'd rows to LDS (stride 260 -> 2-way banks = free). MFMA phase: wave w
// computes N-tile w of rows(16x256) @ sem_w(256x128), accumulates into out.
// mode 0: out = acc + bias; else out += acc.
// ---------------------------------------------------------------------------
__global__ __launch_bounds__(512) void agg_sem_kernel(
    const int* __restrict__ csr_src, const int* __restrict__ off,
    const int* __restrict__ deg,
    const float* __restrict__ el, const float* __restrict__ er,
    const __hip_bfloat16* __restrict__ feat,
    const __hip_bfloat16* __restrict__ Bs_hi, const __hip_bfloat16* __restrict__ Bs_lo,
    const float* __restrict__ bias, float* __restrict__ out, int mode) {
  __shared__ float Arow[16 * LDS_STRIDE];
  const int t = threadIdx.x;
  const int w = t >> 6, lane = t & 63;
  const int hh = lane >> 3;            // head of this lane's 4 channels
  const int node_base = blockIdx.x * 16;
  const ushort* fp = (const ushort*)feat;

  // ---- edge phase: wave w aggregates nodes 2w and 2w+1 ----
#pragma unroll
  for (int i = 0; i < 2; i++) {
    const int node = node_base + 2 * w + i;
    const int n = deg[node];
    const int* lst = csr_src + off[node];
    const float erh = er[node * 8 + hh];

    float aN0 = 0.f, aN1 = 0.f, aN2 = 0.f, aN3 = 0.f, aD = 0.f;
    int j = 0;
    for (; j + 4 <= n; j += 4) {
      int s0 = lst[j], s1 = lst[j + 1], s2 = lst[j + 2], s3 = lst[j + 3];
      float x0 = el[s0 * 8 + hh] + erh;
      float x1 = el[s1 * 8 + hh] + erh;
      float x2 = el[s2 * 8 + hh] + erh;
      float x3 = el[s3 * 8 + hh] + erh;
      ushort4 f0 = *(const ushort4*)(fp + (size_t)s0 * 256 + lane * 4);
      ushort4 f1 = *(const ushort4*)(fp + (size_t)s1 * 256 + lane * 4);
      ushort4 f2 = *(const ushort4*)(fp + (size_t)s2 * 256 + lane * 4);
      ushort4 f3 = *(const ushort4*)(fp + (size_t)s3 * 256 + lane * 4);
      x0 = x0 > 0.f ? x0 : 0.2f * x0;  float e0 = __expf(x0);
      x1 = x1 > 0.f ? x1 : 0.2f * x1;  float e1 = __expf(x1);
      x2 = x2 > 0.f ? x2 : 0.2f * x2;  float e2 = __expf(x2);
      x3 = x3 > 0.f ? x3 : 0.2f * x3;  float e3 = __expf(x3);
      aD += e0 + e1 + e2 + e3;
      aN0 = fmaf(e0, __uint_as_float((unsigned)f0.x << 16), aN0);
      aN1 = fmaf(e0, __uint_as_float((unsigned)f0.y << 16), aN1);
      aN2 = fmaf(e0, __uint_as_float((unsigned)f0.z << 16), aN2);
      aN3 = fmaf(e0, __uint_as_float((unsigned)f0.w << 16), aN3);
      aN0 = fmaf(e1, __uint_as_float((unsigned)f1.x << 16), aN0);
      aN1 = fmaf(e1, __uint_as_float((unsigned)f1.y << 16), aN1);
      aN2 = fmaf(e1, __uint_as_float((unsigned)f1.z << 16), aN2);
      aN3 = fmaf(e1, __uint_as_float((unsigned)f1.w << 16), aN3);
      aN0 = fmaf(e2, __uint_as_float((unsigned)f2.x << 16), aN0);
      aN1 = fmaf(e2, __uint_as_float((unsigned)f2.y << 16), aN1);
      aN2 = fmaf(e2, __uint_as_float((unsigned)f2.z << 16), aN2);
      aN3 = fmaf(e2, __uint_as_float((unsigned)f2.w << 16), aN3);
      aN0 = fmaf(e3, __uint_as_float((unsigned)f3.x << 16), aN0);
      aN1 = fmaf(e3, __uint_as_float((unsigned)f3.y << 16), aN1);
      aN2 = fmaf(e3, __uint_as_float((unsigned)f3.z << 16), aN2);
      aN3 = fmaf(e3, __uint_as_float((unsigned)f3.w << 16), aN3);
    }
    for (; j < n; j++) {
      int s = lst[j];
      float x = el[s * 8 + hh] + erh;
      ushort4 f0 = *(const ushort4*)(fp + (size_t)s * 256 + lane * 4);
      x = x > 0.f ? x : 0.2f * x;
      float e0 = __expf(x);
      aD += e0;
      aN0 = fmaf(e0, __uint_as_float((unsigned)f0.x << 16), aN0);
      aN1 = fmaf(e0, __uint_as_float((unsigned)f0.y << 16), aN1);
      aN2 = fmaf(e0, __uint_as_float((unsigned)f0.z << 16), aN2);
      aN3 = fmaf(e0, __uint_as_float((unsigned)f0.w << 16), aN3);
    }

    float inv = (n > 0) ? 1.f / aD : 0.f;
    float r0 = aN0 * inv, r1 = aN1 * inv, r2 = aN2 * inv, r3 = aN3 * inv;
    r0 = r0 > 0.f ? r0 : (__expf(r0) - 1.f);
    r1 = r1 > 0.f ? r1 : (__expf(r1) - 1.f);
    r2 = r2 > 0.f ? r2 : (__expf(r2) - 1.f);
    r3 = r3 > 0.f ? r3 : (__expf(r3) - 1.f);
    *(float4*)&Arow[(2 * w + i) * LDS_STRIDE + lane * 4] =
        make_float4(r0, r1, r2, r3);
  }
  __syncthreads();

  // ---- MFMA phase: wave w -> N-tile nt = w ----
  const int nt = w;
  const int l15 = lane & 15, quad = lane >> 4;
  v4f acc = {0.f, 0.f, 0.f, 0.f};
#pragma unroll
  for (int kc = 0; kc < 8; kc++) {
    const float* ap = &Arow[l15 * LDS_STRIDE + kc * 32 + quad * 8];
    float4 a0 = *(const float4*)ap;
    float4 a1 = *(const float4*)(ap + 4);
    float fv[8] = {a0.x, a0.y, a0.z, a0.w, a1.x, a1.y, a1.z, a1.w};
    short8 ahi, alo;
#pragma unroll
    for (int q = 0; q < 8; q++) {
      float back, back2;
      ahi[q] = f2bf(fv[q], &back);
      alo[q] = f2bf(fv[q] - back, &back2);
    }
    const int o = ((kc * 8 + nt) * 64 + lane) * 8;
    short8 bhi = *(const short8*)(Bs_hi + o);
    short8 blo = *(const short8*)(Bs_lo + o);
    acc = __builtin_amdgcn_mfma_f32_16x16x32_bf16(ahi, bhi, acc, 0, 0, 0);
    acc = __builtin_amdgcn_mfma_f32_16x16x32_bf16(ahi, blo, acc, 0, 0, 0);
    acc = __builtin_amdgcn_mfma_f32_16x16x32_bf16(alo, bhi, acc, 0, 0, 0);
  }

#pragma unroll
  for (int r = 0; r < 4; r++) {
    int m = node_base + quad * 4 + r;
    size_t o = (size_t)m * 128 + nt * 16 + l15;
    float v = acc[r];
    if (mode == 0) v += bias[nt * 16 + l15];
    else           v += out[o];
    out[o] = v;
  }
}

// ---------------------------------------------------------------------------
extern "C" void kernel_launch(void* const* d_in, const int* in_sizes, int n_in,
                              void* d_out, int out_size, void* d_ws, size_t ws_size,
                              hipStream_t stream) {
  const float* h      = (const float*)d_in[0];
  const int*   ei     = (const int*)d_in[1];
  const float* fc_w   = (const float*)d_in[2];
  const float* attn_l = (const float*)d_in[3];
  const float* attn_r = (const float*)d_in[4];
  const float* sem_w  = (const float*)d_in[5];
  const float* sem_b  = (const float*)d_in[6];
  float* out = (float*)d_out;

  // workspace layout (bytes) — total ~118.4 MB (<=132.8 MB proven safe)
  char* ws = (char*)d_ws;
  __hip_bfloat16* feat3 = (__hip_bfloat16*)ws;                     // 76.8 MB
  float* el3     = (float*)(ws + 76800000);                        // 4.8 MB
  float* er3     = (float*)(ws + 81600000);                        // 4.8 MB
  int*   csr_src = (int*)(ws + 86400000);                          // 9.6 MB
  int2*  ebuf    = (int2*)(ws + 96000000);                         // 19.2 MB
  int*   deg3    = (int*)(ws + 115200000);                         // 0.6 MB
  int*   off3    = (int*)(ws + 115800000);                         // 0.6 MB
  int*   cntmat  = (int*)(ws + 116400000);                         // 602 KB
  int*   posm    = (int*)(ws + 117050000);                         // 602 KB
  int*   btot    = (int*)(ws + 117700000);                         // 2.4 KB
  int*   boff    = (int*)(ws + 117710000);                         // 2.4 KB
  __hip_bfloat16* Wf_hi = (__hip_bfloat16*)(ws + 117800000);       // 3x69632 B
  __hip_bfloat16* Wf_lo = (__hip_bfloat16*)(ws + 118050000);       // 3x69632 B
  __hip_bfloat16* Bs_hi = (__hip_bfloat16*)(ws + 118300000);       // 3x65536 B
  __hip_bfloat16* Bs_lo = (__hip_bfloat16*)(ws + 118550000);       // 3x65536 B

  // --- CSR build (deterministic counting sort) + fused weight prep ---
  blk_count_kernel<<<NCHUNKBLK, 256, 0, stream>>>(ei, cntmat);
  col_scan_kernel<<<NBKT3, 256, 0, stream>>>(cntmat, posm, btot);
  bucket_scan_kernel<<<1, 1024, 0, stream>>>(btot, boff);
  scatter_det_kernel<<<NCHUNKBLK, 256, 0, stream>>>(ei, boff, posm, ebuf);
  bucket_csr_kernel<<<NBKT3, 256, 0, stream>>>(ebuf, boff, btot, off3, deg3, csr_src);
  prep_kernel<<<NPATH * 33, 256, 0, stream>>>(fc_w, attn_l, attn_r, sem_w,
                                              Wf_hi, Wf_lo, Bs_hi, Bs_lo);

  // --- all 3 feat GEMMs in one dispatch ---
  feat_mfma_kernel<<<dim3(N_NODES / 16, NPATH), 64, 0, stream>>>(
      h, Wf_hi, Wf_lo, feat3, el3, er3);

  // --- fused aggregate + semantic GEMM per path (out accumulates) ---
  for (int p = 0; p < NPATH; p++) {
    agg_sem_kernel<<<N_NODES / 16, 512, 0, stream>>>(
        csr_src, off3 + p * N_NODES, deg3 + p * N_NODES,
        el3 + (size_t)p * N_NODES * 8, er3 + (size_t)p * N_NODES * 8,
        feat3 + (size_t)p * N_NODES * 256,
        Bs_hi + (size_t)p * 32768, Bs_lo + (size_t)p * 32768,
        sem_b, out, p);
  }
}